// Round 4
// baseline (252.827 us; speedup 1.0000x reference)
//
#include <hip/hip_runtime.h>
#include <hip/hip_bf16.h>

// SpatialTransformer: 3D trilinear warp, zeros padding.
// src [B,C,D,H,W] f32 = [2,2,128,160,128]; flow [B,3,D,H,W]; out [B,C,D,H,W].
//
// R4: R3's LDS tiling was latency-bound at 36% occupancy (40KB LDS, 4-wave
// blocks -> <=16 waves/CU). Fix: 512-thread blocks (8 waves) -> 4 blocks/CU
// = 32 waves/CU cap; cache flow in registers across the channel loop so flow
// is read from HBM once (-63 MB).
// Tile: out 32x8x8, cached (40 x 16 x 16) f32 = 40 KB LDS; halo R=4 covers
// all but ~2e-4 of voxels (flow ~ N(0,1)); rare lanes take exact global
// fallback.

#define B_ 2
#define C_ 2
#define D_ 128
#define H_ 160
#define W_ 128
constexpr int S_ = D_ * H_ * W_;

#define ZT 8
#define YT 8
#define XT 32
#define R_ 4
#define CZ (ZT + 2 * R_)   // 16
#define CY (YT + 2 * R_)   // 16
#define CX (XT + 2 * R_)   // 40
#define NTHREADS 512
#define VPT 4              // voxels per thread per channel (2048/512)

__device__ __forceinline__ float pair_val(const float* p, bool hi0, bool lo1,
                                          float wx0, float wx1) {
    const float v0 = hi0 ? p[1] : p[0];
    const float v1 = lo1 ? p[0] : p[1];
    return wx0 * v0 + wx1 * v1;
}

__global__ __launch_bounds__(NTHREADS, 6) void warp3d_tile(
    const float* __restrict__ src,
    const float* __restrict__ flow,
    float* __restrict__ out)
{
    __shared__ float tile[CZ * CY * CX];   // 10240 floats = 40 KB

    const int tid = threadIdx.x;
    const int xb = blockIdx.x * XT;
    const int yb = blockIdx.y * YT;
    const int zb = (blockIdx.z & 15) * ZT;
    const int b  = blockIdx.z >> 4;

    const int zlo = max(0, zb - R_), zhi = min(D_, zb + ZT + R_);
    const int ylo = max(0, yb - R_), yhi = min(H_, yb + YT + R_);
    const int xlo = max(0, xb - R_), xhi = min(W_, xb + XT + R_);

    const float* fb = flow + (long long)b * 3 * S_;

    // flow cache across the channel loop (registers)
    float fzc[VPT], fyc[VPT], fxc[VPT];

    for (int ch = 0; ch < C_; ++ch) {
        const float* sc = src + ((long long)b * C_ + ch) * S_;
        float* oc       = out + ((long long)b * C_ + ch) * S_;

        if (ch) __syncthreads();           // tile reads done before restage

        // ---- stage src tile (+halo): 2560 float4 chunks, 5 per thread ----
#pragma unroll
        for (int j = 0; j < 5; ++j) {
            const int lin = j * NTHREADS + tid;    // 0..2559
            const int row = lin / 10;              // 0..255  (rz*16+ry)
            const int c   = lin - row * 10;        // 0..9
            const int rz = row >> 4, ry = row & 15;
            const int gz = zb - R_ + rz;
            const int gy = yb - R_ + ry;
            const int gx = xb - R_ + c * 4;
            if ((unsigned)gz < (unsigned)D_ && (unsigned)gy < (unsigned)H_ &&
                (unsigned)gx <= (unsigned)(W_ - 4)) {
                const float4 v = *(const float4*)(sc + ((gz * H_ + gy) << 7) + gx);
                *(float4*)&tile[row * CX + c * 4] = v;
            }
        }
        __syncthreads();

        // ---- compute: 2048 voxels, 4 per thread ----
#pragma unroll
        for (int it = 0; it < VPT; ++it) {
            const int vox = it * NTHREADS + tid;
            const int lx = vox & 31, ly = (vox >> 5) & 7, lz = vox >> 8;
            const int x = xb + lx, y = yb + ly, z = zb + lz;
            const int s = ((z * H_ + y) << 7) + x;

            float fz, fy, fx;
            if (ch == 0) {
                fz = fb[s]; fy = fb[S_ + s]; fx = fb[2 * S_ + s];
                fzc[it] = fz; fyc[it] = fy; fxc[it] = fx;
            } else {
                fz = fzc[it]; fy = fyc[it]; fx = fxc[it];
            }

            const float iz = (float)z + fz;
            const float iy = (float)y + fy;
            const float ix = (float)x + fx;

            const float zf = floorf(iz), yf = floorf(iy), xf = floorf(ix);
            const float tz = iz - zf, ty = iy - yf, tx = ix - xf;
            const int z0 = (int)zf, y0 = (int)yf, x0 = (int)xf;

            const int zc0 = min(max(z0, 0), D_ - 1), zc1 = min(max(z0 + 1, 0), D_ - 1);
            const int yc0 = min(max(y0, 0), H_ - 1), yc1 = min(max(y0 + 1, 0), H_ - 1);
            const int xp  = min(max(x0, 0), W_ - 2);

            const float wz0 = ((unsigned)z0       < (unsigned)D_) ? (1.f - tz) : 0.f;
            const float wz1 = ((unsigned)(z0 + 1) < (unsigned)D_) ? tz         : 0.f;
            const float wy0 = ((unsigned)y0       < (unsigned)H_) ? (1.f - ty) : 0.f;
            const float wy1 = ((unsigned)(y0 + 1) < (unsigned)H_) ? ty         : 0.f;
            const float wx0 = ((unsigned)x0       < (unsigned)W_) ? (1.f - tx) : 0.f;
            const float wx1 = ((unsigned)(x0 + 1) < (unsigned)W_) ? tx         : 0.f;
            const bool hi0 = x0 > xp;   // x0 == W-1
            const bool lo1 = x0 < xp;   // x0 == -1

            const bool fast = (zc0 >= zlo) & (zc1 < zhi) &
                              (yc0 >= ylo) & (yc1 < yhi) &
                              (xp >= xlo) & (xp + 1 < xhi);

            float acc;
            if (fast) {
                const int izl0 = zc0 - (zb - R_), izl1 = zc1 - (zb - R_);
                const int iyl0 = yc0 - (yb - R_), iyl1 = yc1 - (yb - R_);
                const int ixl  = xp - (xb - R_);
                const float* t00 = &tile[(izl0 * CY + iyl0) * CX + ixl];
                const float* t01 = &tile[(izl0 * CY + iyl1) * CX + ixl];
                const float* t10 = &tile[(izl1 * CY + iyl0) * CX + ixl];
                const float* t11 = &tile[(izl1 * CY + iyl1) * CX + ixl];
                const float p00 = pair_val(t00, hi0, lo1, wx0, wx1);
                const float p01 = pair_val(t01, hi0, lo1, wx0, wx1);
                const float p10 = pair_val(t10, hi0, lo1, wx0, wx1);
                const float p11 = pair_val(t11, hi0, lo1, wx0, wx1);
                acc = wz0 * (wy0 * p00 + wy1 * p01) + wz1 * (wy0 * p10 + wy1 * p11);
            } else {
                const float* g00 = sc + ((zc0 * H_ + yc0) << 7) + xp;
                const float* g01 = sc + ((zc0 * H_ + yc1) << 7) + xp;
                const float* g10 = sc + ((zc1 * H_ + yc0) << 7) + xp;
                const float* g11 = sc + ((zc1 * H_ + yc1) << 7) + xp;
                const float p00 = pair_val(g00, hi0, lo1, wx0, wx1);
                const float p01 = pair_val(g01, hi0, lo1, wx0, wx1);
                const float p10 = pair_val(g10, hi0, lo1, wx0, wx1);
                const float p11 = pair_val(g11, hi0, lo1, wx0, wx1);
                acc = wz0 * (wy0 * p00 + wy1 * p01) + wz1 * (wy0 * p10 + wy1 * p11);
            }
            oc[s] = acc;
        }
    }
}

extern "C" void kernel_launch(void* const* d_in, const int* in_sizes, int n_in,
                              void* d_out, int out_size, void* d_ws, size_t ws_size,
                              hipStream_t stream) {
    const float* src  = (const float*)d_in[0];
    const float* flow = (const float*)d_in[1];
    float* out = (float*)d_out;

    dim3 grid(W_ / XT, H_ / YT, (D_ / ZT) * B_);   // 4 x 20 x 32
    warp3d_tile<<<grid, NTHREADS, 0, stream>>>(src, flow, out);
}